// Round 6
// baseline (127.060 us; speedup 1.0000x reference)
//
#include <hip/hip_runtime.h>
#include <math.h>

#define BS 8
#define SEQ 1024
#define DIM 1024
#define FF 4096
#define NE 8
#define NSLOT 16
#define MAXM 8
#define NCHUNK 64

// ws float offsets
#define WS_LPART 0                              // 4096
#define WS_SELW  (WS_LPART + BS*NCHUNK*NE)      // 16
#define WS_SELE  (WS_SELW + NSLOT)              // 16 (ints)
#define WS_ACT   (WS_SELE + NSLOT)              // [NSLOT][FF] = 65536
#define WS_Y     (WS_ACT + NSLOT*FF)            // [NSLOT][DIM] = 16384

__device__ __forceinline__ float dot4(float4 a, float4 b) {
    return a.x*b.x + a.y*b.y + a.z*b.z + a.w*b.w;
}

// ---- 1. h-chunk sum fused with router dot ----
__global__ __launch_bounds__(256) void klogit(const float4* __restrict__ h4,
                                              const float4* __restrict__ rw4,
                                              float* __restrict__ lpart) {
    const int c = blockIdx.x, b = blockIdx.y, t = threadIdx.x;
    const float4* p = h4 + ((size_t)b * SEQ + (size_t)c * 16) * (DIM/4) + t;
    float4 s = make_float4(0.f, 0.f, 0.f, 0.f);
    #pragma unroll
    for (int i = 0; i < 16; ++i) {
        float4 v = p[(size_t)i * (DIM/4)];
        s.x += v.x; s.y += v.y; s.z += v.z; s.w += v.w;
    }
    __shared__ float red[4];
    const int wave = t >> 6, lane = t & 63;
    for (int e = 0; e < NE; ++e) {
        float pd = dot4(s, rw4[(size_t)e * (DIM/4) + t]);
        #pragma unroll
        for (int o = 32; o; o >>= 1) pd += __shfl_xor(pd, o);
        if (lane == 0) red[wave] = pd;
        __syncthreads();
        if (t == 0) lpart[(size_t)(b * NCHUNK + c) * NE + e] = red[0]+red[1]+red[2]+red[3];
        __syncthreads();
    }
}

// ---- 2. final logits + softmax + top2 ----
__global__ void krouter2(const float* __restrict__ lpart,
                         float* __restrict__ out_logits,
                         float* __restrict__ selw, int* __restrict__ sele) {
    const int t = threadIdx.x;  // 64
    __shared__ float lg[BS * NE];
    if (t < BS * NE) {
        const int b = t >> 3, e = t & 7;
        float s = 0.f;
        for (int c = 0; c < NCHUNK; ++c) s += lpart[(size_t)(b * NCHUNK + c) * NE + e];
        s *= (1.0f / (float)SEQ);
        lg[b * NE + e] = s;
        out_logits[b * NE + e] = s;
    }
    __syncthreads();
    if (t < BS) {
        float l[NE]; float mx = -1e30f;
        #pragma unroll
        for (int e = 0; e < NE; ++e) { l[e] = lg[t * NE + e]; mx = fmaxf(mx, l[e]); }
        float sum = 0.f;
        #pragma unroll
        for (int e = 0; e < NE; ++e) { l[e] = expf(l[e] - mx); sum += l[e]; }
        const float invs = 1.f / sum;
        float v1 = -1.f, v2 = -1.f; int e1 = -1, e2 = -1;
        #pragma unroll
        for (int e = 0; e < NE; ++e) {
            float pe = l[e] * invs;
            if (pe > v1)      { v2 = v1; e2 = e1; v1 = pe; e1 = e; }
            else if (pe > v2) { v2 = pe; e2 = e; }
        }
        selw[t * 2 + 0] = v1; sele[t * 2 + 0] = e1;
        selw[t * 2 + 1] = v2; sele[t * 2 + 1] = e2;
    }
}

__device__ __forceinline__ int build_slots(const int* __restrict__ sele, int e, int* slot) {
    unsigned mask = 0;
    #pragma unroll
    for (int s = 0; s < NSLOT; ++s) mask |= (sele[s] == e) ? (1u << s) : 0u;
    const int m = __popc(mask);
    unsigned mm = mask;
    #pragma unroll
    for (int ti = 0; ti < MAXM; ++ti) { slot[ti] = __ffs(mm) - 1; mm &= mm - 1; }
    return m;
}

// ======== 3. fused up/gate/silu: wave-per-row, contiguous 1KB loads ========
// LD: 8 independent float4 loads (8KB/wave); COMP after; reg ping-pong prefetch.
#define SW_LD(Ar, Br, R8) {                                            \
    const size_t rb_ = (size_t)(rowbase + (R8)) * 256 + lane;          \
    _Pragma("unroll")                                                  \
    for (int i_ = 0; i_ < 4; ++i_) {                                   \
        Ar[i_] = w1e4[rb_ + i_ * 64];                                  \
        Br[i_] = w3e4[rb_ + i_ * 64];                                  \
    } }

template<int MM>
__device__ void swiglu_body(const float4* __restrict__ w1e4,
                            const float4* __restrict__ w3e4,
                            const float4* __restrict__ xs4,
                            float* __restrict__ act,
                            const int* slot, int m, int rowbase, int lane) {
    float4 A0[4], B0[4], A1[4], B1[4];
    SW_LD(A0, B0, 0)
    for (int r8 = 0; r8 < 8; r8 += 2) {
        SW_LD(A1, B1, r8 + 1)
        {   // COMP(A0,B0,r8)
            const int row = rowbase + r8;
            #pragma unroll
            for (int ti = 0; ti < MM; ++ti) {
                float u = 0.f, g = 0.f;
                #pragma unroll
                for (int i = 0; i < 4; ++i) {
                    float4 x = xs4[ti * 256 + i * 64 + lane];
                    u += dot4(A0[i], x); g += dot4(B0[i], x);
                }
                #pragma unroll
                for (int o = 32; o; o >>= 1) { u += __shfl_xor(u, o); g += __shfl_xor(g, o); }
                if (ti < m && lane == 0)
                    act[(size_t)slot[ti] * FF + row] = (u / (1.f + expf(-u))) * g;
            }
        }
        if (r8 + 2 < 8) SW_LD(A0, B0, r8 + 2)
        {   // COMP(A1,B1,r8+1)
            const int row = rowbase + r8 + 1;
            #pragma unroll
            for (int ti = 0; ti < MM; ++ti) {
                float u = 0.f, g = 0.f;
                #pragma unroll
                for (int i = 0; i < 4; ++i) {
                    float4 x = xs4[ti * 256 + i * 64 + lane];
                    u += dot4(A1[i], x); g += dot4(B1[i], x);
                }
                #pragma unroll
                for (int o = 32; o; o >>= 1) { u += __shfl_xor(u, o); g += __shfl_xor(g, o); }
                if (ti < m && lane == 0)
                    act[(size_t)slot[ti] * FF + row] = (u / (1.f + expf(-u))) * g;
            }
        }
    }
}

__global__ __launch_bounds__(256) void kswiglu(const float* __restrict__ h,
                                               const float* __restrict__ w1,
                                               const float* __restrict__ w3,
                                               const int* __restrict__ sele,
                                               float* __restrict__ act) {
    __shared__ float xs[MAXM * DIM];   // 32 KB
    const int tile = blockIdx.x, e = blockIdx.y, t = threadIdx.x;
    int slot[MAXM];
    const int m = build_slots(sele, e, slot);
    if (m == 0) return;
    {   // stage x rows (zero-fill unused slots -> no guards in inner loop)
        const int ti = t >> 5, j = t & 31;
        float4* dst = (float4*)(xs + ti * DIM);
        if (ti < m) {
            const int s = slot[ti];
            const float4* src = (const float4*)(h + ((size_t)((s >> 1) * SEQ + (s & 1))) * DIM);
            #pragma unroll
            for (int i = 0; i < 8; ++i) dst[j + i * 32] = src[j + i * 32];
        } else {
            const float4 z = make_float4(0.f, 0.f, 0.f, 0.f);
            #pragma unroll
            for (int i = 0; i < 8; ++i) dst[j + i * 32] = z;
        }
    }
    __syncthreads();
    const int wave = t >> 6, lane = t & 63;
    const int rowbase = tile * 32 + wave * 8;
    const float4* w1e4 = (const float4*)w1 + (size_t)e * FF * (DIM/4);
    const float4* w3e4 = (const float4*)w3 + (size_t)e * FF * (DIM/4);
    if (m <= 4) swiglu_body<4>(w1e4, w3e4, (const float4*)xs, act, slot, m, rowbase, lane);
    else        swiglu_body<8>(w1e4, w3e4, (const float4*)xs, act, slot, m, rowbase, lane);
}

// ======== 4. down proj: wave-per-row, act chunked through LDS ========
template<int MM>
__device__ void down_body(const float4* __restrict__ w2e4,
                          const float* __restrict__ act,
                          const float* __restrict__ selw,
                          float* __restrict__ y,
                          const int* slot, int m, int tile, int t, float* xs) {
    const int wave = t >> 6, lane = t & 63;
    const int rowbase = tile * 16 + wave * 4;
    float acc[4][MM];
    #pragma unroll
    for (int r = 0; r < 4; ++r)
        #pragma unroll
        for (int ti = 0; ti < MM; ++ti) acc[r][ti] = 0.f;

    for (int c = 0; c < 4; ++c) {
        __syncthreads();
        {   // stage act chunk c (zero-fill unused)
            const int ti = t >> 5, j = t & 31;
            float4* dst = (float4*)(xs + ti * 1024);
            if (ti < m) {
                const float4* src = (const float4*)(act + (size_t)slot[ti] * FF + c * 1024);
                #pragma unroll
                for (int i = 0; i < 8; ++i) dst[j + i * 32] = src[j + i * 32];
            } else {
                const float4 z = make_float4(0.f, 0.f, 0.f, 0.f);
                #pragma unroll
                for (int i = 0; i < 8; ++i) dst[j + i * 32] = z;
            }
        }
        __syncthreads();
        float4 W[4][4];
        #pragma unroll
        for (int r = 0; r < 4; ++r) {
            const size_t rb = (size_t)(rowbase + r) * (FF/4) + c * 256 + lane;
            #pragma unroll
            for (int i = 0; i < 4; ++i) W[r][i] = w2e4[rb + i * 64];
        }
        const float4* xs4 = (const float4*)xs;
        #pragma unroll
        for (int i = 0; i < 4; ++i) {
            #pragma unroll
            for (int ti = 0; ti < MM; ++ti) {
                float4 x = xs4[ti * 256 + i * 64 + lane];
                #pragma unroll
                for (int r = 0; r < 4; ++r) acc[r][ti] += dot4(W[r][i], x);
            }
        }
    }
    #pragma unroll
    for (int r = 0; r < 4; ++r) {
        #pragma unroll
        for (int ti = 0; ti < MM; ++ti) {
            float v = acc[r][ti];
            #pragma unroll
            for (int o = 32; o; o >>= 1) v += __shfl_xor(v, o);
            if (ti < m && lane == 0)
                y[(size_t)slot[ti] * DIM + rowbase + r] = selw[slot[ti]] * v;
        }
    }
}

__global__ __launch_bounds__(256) void kdown(const float* __restrict__ w2,
                                             const float* __restrict__ act,
                                             const int* __restrict__ sele,
                                             const float* __restrict__ selw,
                                             float* __restrict__ y) {
    __shared__ float xs[MAXM * 1024];   // 32 KB
    const int tile = blockIdx.x, e = blockIdx.y, t = threadIdx.x;
    int slot[MAXM];
    const int m = build_slots(sele, e, slot);
    if (m == 0) return;
    const float4* w2e4 = (const float4*)w2 + (size_t)e * DIM * (FF/4);
    if (m <= 4) down_body<4>(w2e4, act, selw, y, slot, m, tile, t, xs);
    else        down_body<8>(w2e4, act, selw, y, slot, m, tile, t, xs);
}

// ---- 5. combine two selections per batch, broadcast across L ----
__global__ __launch_bounds__(256) void kbcast(const float4* __restrict__ y4,
                                              float4* __restrict__ out4) {
    const int b = blockIdx.y, lg = blockIdx.x, t = threadIdx.x;
    float4 y0 = y4[(size_t)(2 * b) * (DIM/4) + t];
    float4 y1 = y4[(size_t)(2 * b + 1) * (DIM/4) + t];
    float4 c = make_float4(y0.x + y1.x, y0.y + y1.y, y0.z + y1.z, y0.w + y1.w);
    size_t base = ((size_t)b * SEQ + (size_t)lg * 8) * (DIM/4) + t;
    #pragma unroll
    for (int i = 0; i < 8; ++i) out4[base + (size_t)i * (DIM/4)] = c;
}

extern "C" void kernel_launch(void* const* d_in, const int* in_sizes, int n_in,
                              void* d_out, int out_size, void* d_ws, size_t ws_size,
                              hipStream_t stream) {
    const float* h  = (const float*)d_in[0];
    const float* rw = (const float*)d_in[1];
    const float* w1 = (const float*)d_in[2];
    const float* w2 = (const float*)d_in[3];
    const float* w3 = (const float*)d_in[4];
    float* out = (float*)d_out;
    float* ws  = (float*)d_ws;

    float* lpart = ws + WS_LPART;
    float* selw  = ws + WS_SELW;
    int*   sele  = (int*)(ws + WS_SELE);
    float* act   = ws + WS_ACT;
    float* y     = ws + WS_Y;
    float* out_logits = out + (size_t)BS * SEQ * DIM;

    klogit  <<<dim3(NCHUNK, BS), 256, 0, stream>>>((const float4*)h, (const float4*)rw, lpart);
    krouter2<<<1, 64, 0, stream>>>(lpart, out_logits, selw, sele);
    kswiglu <<<dim3(FF / 32, NE), 256, 0, stream>>>(h, w1, w3, sele, act);
    kdown   <<<dim3(DIM / 16, NE), 256, 0, stream>>>(w2, act, sele, selw, y);
    kbcast  <<<dim3(SEQ / 8, BS), 256, 0, stream>>>((const float4*)y, (float4*)out);
}